// Round 1
// baseline (2128.522 us; speedup 1.0000x reference)
//
#include <hip/hip_runtime.h>
#include <math.h>

#define B_SZ  2
#define L_SEQ 8192
#define EMB   1024
#define NH    16
#define HDIM  64
#define WIN   128

// ---------------- GEMM: C = A @ B^T + bias ----------------
// A: (M,K) row-major, Bm: (N,K) row-major, C: (M,N)
// LAYOUT 0: C standard (M,N).  LAYOUT 1: scatter to (B,H,L,HD) for q/k/v.
template<int LAYOUT>
__global__ __launch_bounds__(256)
void gemm_bias(const float* __restrict__ A, const float* __restrict__ Bm,
               const float* __restrict__ bias, float* __restrict__ C)
{
    constexpr int BM = 128, BN = 128, BK = 16;
    const int N = EMB, K = EMB;
    __shared__ float As[BK][BM + 4];
    __shared__ float Bs[BK][BN + 4];
    const int t  = threadIdx.x;
    const int tx = t & 15, ty = t >> 4;
    const int bm = blockIdx.y * BM, bn = blockIdx.x * BN;
    const float* Ap = A  + (size_t)bm * K;
    const float* Bp = Bm + (size_t)bn * K;
    float acc[8][8] = {};

    for (int k0 = 0; k0 < K; k0 += BK) {
        #pragma unroll
        for (int i = 0; i < 2; i++) {
            int fid = i * 256 + t;          // 0..511 float4 slots per tile
            int row = fid >> 2;             // 0..127
            int kq  = (fid & 3) << 2;       // 0,4,8,12
            float4 va = *(const float4*)(Ap + (size_t)row * K + k0 + kq);
            As[kq+0][row] = va.x; As[kq+1][row] = va.y;
            As[kq+2][row] = va.z; As[kq+3][row] = va.w;
            float4 vb = *(const float4*)(Bp + (size_t)row * K + k0 + kq);
            Bs[kq+0][row] = vb.x; Bs[kq+1][row] = vb.y;
            Bs[kq+2][row] = vb.z; Bs[kq+3][row] = vb.w;
        }
        __syncthreads();
        #pragma unroll
        for (int kk = 0; kk < BK; kk++) {
            float a[8], b[8];
            *(float4*)&a[0] = *(const float4*)&As[kk][ty*8];
            *(float4*)&a[4] = *(const float4*)&As[kk][ty*8+4];
            *(float4*)&b[0] = *(const float4*)&Bs[kk][tx*8];
            *(float4*)&b[4] = *(const float4*)&Bs[kk][tx*8+4];
            #pragma unroll
            for (int i2 = 0; i2 < 8; i2++)
                #pragma unroll
                for (int j2 = 0; j2 < 8; j2++)
                    acc[i2][j2] = fmaf(a[i2], b[j2], acc[i2][j2]);
        }
        __syncthreads();
    }

    float bv[8];
    #pragma unroll
    for (int j = 0; j < 8; j++) bv[j] = bias[bn + tx*8 + j];
    #pragma unroll
    for (int i = 0; i < 8; i++) {
        int m = bm + ty*8 + i;
        float4 r0 = make_float4(acc[i][0]+bv[0], acc[i][1]+bv[1],
                                acc[i][2]+bv[2], acc[i][3]+bv[3]);
        float4 r1 = make_float4(acc[i][4]+bv[4], acc[i][5]+bv[5],
                                acc[i][6]+bv[6], acc[i][7]+bv[7]);
        if (LAYOUT == 0) {
            float* p = C + (size_t)m * N + bn + tx*8;
            *(float4*)p = r0; *(float4*)(p + 4) = r1;
        } else {
            // m = b*L + l ; n = h*64 + d  ->  ((b*NH+h)*L + l)*64 + d
            int bb = m >> 13, l = m & (L_SEQ - 1);
            int n  = bn + tx*8;
            int h  = n >> 6, d = n & 63;   // 8 consecutive n never cross a head
            float* p = C + ((size_t)(bb*NH + h) * L_SEQ + l) * HDIM + d;
            *(float4*)p = r0; *(float4*)(p + 4) = r1;
        }
    }
}

// ---------------- banded flash attention ----------------
// grid: (L/64, B*H), block 256.  Each block: 64 queries of one (b,h).
// 5 key tiles of 64 cover [q0-128, q0+191]; online softmax; scale 1/8 folded
// into Q load.
__global__ __launch_bounds__(256)
void attn_kernel(const float* __restrict__ qb, const float* __restrict__ kb,
                 const float* __restrict__ vb, float* __restrict__ ctx)
{
    __shared__ float Qs[HDIM * 68];   // transposed [d][r], pre-scaled by 1/8
    __shared__ float KVs[64 * 68];    // K phase: [d][c] ; V phase: [p][d]
    __shared__ float Ps[64 * 68];     // S/P transposed: [c][r]
    __shared__ float red[4][64];
    __shared__ float m_run[64], l_run[64], alf[64];

    const int t  = threadIdx.x;
    const int tx = t & 15, ty = t >> 4;
    const int bh = blockIdx.y;
    const int q0 = blockIdx.x * 64;
    const float* qp = qb + ((size_t)bh * L_SEQ + q0) * HDIM;
    const float* kp = kb + (size_t)bh * L_SEQ * HDIM;
    const float* vp = vb + (size_t)bh * L_SEQ * HDIM;

    #pragma unroll
    for (int i = 0; i < 4; i++) {
        int fid = i * 256 + t;            // 1024 float4 slots
        int r  = fid >> 4;
        int d0 = (fid & 15) << 2;
        float4 v = *(const float4*)(qp + (size_t)r * HDIM + d0);
        Qs[(d0+0)*68 + r] = v.x * 0.125f;
        Qs[(d0+1)*68 + r] = v.y * 0.125f;
        Qs[(d0+2)*68 + r] = v.z * 0.125f;
        Qs[(d0+3)*68 + r] = v.w * 0.125f;
    }
    if (t < 64) { m_run[t] = -3e38f; l_run[t] = 0.0f; }
    float o[4][4] = {};
    __syncthreads();

    for (int kt = 0; kt < 5; kt++) {
        const int p0 = q0 - WIN + kt * 64;
        // ---- load K tile transposed ----
        #pragma unroll
        for (int i = 0; i < 4; i++) {
            int fid = i * 256 + t;
            int c  = fid >> 4;
            int d0 = (fid & 15) << 2;
            int p  = p0 + c;
            float4 v = make_float4(0.f, 0.f, 0.f, 0.f);
            if (p >= 0 && p < L_SEQ) v = *(const float4*)(kp + (size_t)p * HDIM + d0);
            KVs[(d0+0)*68 + c] = v.x;
            KVs[(d0+1)*68 + c] = v.y;
            KVs[(d0+2)*68 + c] = v.z;
            KVs[(d0+3)*68 + c] = v.w;
        }
        __syncthreads();
        // ---- S = Q K^T (scaled) ----
        float s[4][4] = {};
        #pragma unroll
        for (int d = 0; d < HDIM; d++) {
            float a[4], b[4];
            *(float4*)a = *(const float4*)&Qs[d*68 + ty*4];
            *(float4*)b = *(const float4*)&KVs[d*68 + tx*4];
            #pragma unroll
            for (int i = 0; i < 4; i++)
                #pragma unroll
                for (int j = 0; j < 4; j++)
                    s[i][j] = fmaf(a[i], b[j], s[i][j]);
        }
        // ---- band + bounds mask ----
        #pragma unroll
        for (int i = 0; i < 4; i++)
            #pragma unroll
            for (int j = 0; j < 4; j++) {
                int r = ty*4 + i, c = tx*4 + j;
                int p = p0 + c;
                int delta = p - (q0 + r);
                if (p < 0 || p >= L_SEQ || delta < -WIN || delta > WIN)
                    s[i][j] = -3e38f;
            }
        __syncthreads();           // all K reads done; KVs free for V
        // ---- write raw S (transposed), load V tile ----
        #pragma unroll
        for (int i = 0; i < 4; i++)
            #pragma unroll
            for (int j = 0; j < 4; j++)
                Ps[(tx*4+j)*68 + ty*4 + i] = s[i][j];
        #pragma unroll
        for (int i = 0; i < 4; i++) {
            int fid = i * 256 + t;
            int c  = fid >> 4;
            int d0 = (fid & 15) << 2;
            int p  = p0 + c;
            float4 v = make_float4(0.f, 0.f, 0.f, 0.f);
            if (p >= 0 && p < L_SEQ) v = *(const float4*)(vp + (size_t)p * HDIM + d0);
            *(float4*)&KVs[c*68 + d0] = v;
        }
        __syncthreads();
        // ---- online softmax: partial row max ----
        {
            int r = t & 63, ch = t >> 6;
            float mx = -3e38f;
            #pragma unroll
            for (int cc = 0; cc < 16; cc++)
                mx = fmaxf(mx, Ps[(ch*16+cc)*68 + r]);
            red[ch][r] = mx;
        }
        __syncthreads();
        if (t < 64) {
            float mloc = fmaxf(fmaxf(red[0][t], red[1][t]),
                               fmaxf(red[2][t], red[3][t]));
            float mold = m_run[t];
            float mnew = fmaxf(mold, mloc);
            m_run[t] = mnew;
            alf[t] = __expf(mold - mnew);   // 1 on fully-masked-so-far rows
        }
        __syncthreads();
        // ---- exp + partial row sum (in place) ----
        {
            int r = t & 63, ch = t >> 6;
            float mnew = m_run[r];
            float sum = 0.0f;
            #pragma unroll
            for (int cc = 0; cc < 16; cc++) {
                int c = ch*16 + cc;
                float pv = __expf(Ps[c*68 + r] - mnew);
                Ps[c*68 + r] = pv;
                sum += pv;
            }
            red[ch][r] = sum;
        }
        __syncthreads();
        if (t < 64)
            l_run[t] = l_run[t] * alf[t]
                     + red[0][t] + red[1][t] + red[2][t] + red[3][t];
        // ---- rescale O, accumulate P @ V ----
        float al[4];
        #pragma unroll
        for (int i = 0; i < 4; i++) al[i] = alf[ty*4 + i];
        #pragma unroll
        for (int i = 0; i < 4; i++)
            #pragma unroll
            for (int j = 0; j < 4; j++) o[i][j] *= al[i];
        #pragma unroll
        for (int p = 0; p < 64; p++) {
            float a[4], b[4];
            *(float4*)a = *(const float4*)&Ps[p*68 + ty*4];
            *(float4*)b = *(const float4*)&KVs[p*68 + tx*4];
            #pragma unroll
            for (int i = 0; i < 4; i++)
                #pragma unroll
                for (int j = 0; j < 4; j++)
                    o[i][j] = fmaf(a[i], b[j], o[i][j]);
        }
        __syncthreads();
    }

    // ---- normalize + store ctx in (B,L,E) ----
    const int bb = bh >> 4, hh = bh & 15;
    #pragma unroll
    for (int i = 0; i < 4; i++) {
        float inv = 1.0f / l_run[ty*4 + i];
        int l = q0 + ty*4 + i;
        float4 r0 = make_float4(o[i][0]*inv, o[i][1]*inv,
                                o[i][2]*inv, o[i][3]*inv);
        *(float4*)(ctx + ((size_t)bb * L_SEQ + l) * EMB + hh * HDIM + tx*4) = r0;
    }
}

extern "C" void kernel_launch(void* const* d_in, const int* in_sizes, int n_in,
                              void* d_out, int out_size, void* d_ws, size_t ws_size,
                              hipStream_t stream) {
    const float* x  = (const float*)d_in[0];
    const float* Wq = (const float*)d_in[1];
    const float* Wk = (const float*)d_in[2];
    const float* Wv = (const float*)d_in[3];
    const float* Wo = (const float*)d_in[4];
    const float* bq = (const float*)d_in[5];
    const float* bk = (const float*)d_in[6];
    const float* bv = (const float*)d_in[7];
    const float* bo = (const float*)d_in[8];
    float* out = (float*)d_out;

    float* ws = (float*)d_ws;
    const size_t per = (size_t)B_SZ * NH * L_SEQ * HDIM;  // 16.7M floats
    float* qb = ws;
    float* kb = ws + per;
    float* vb = ws + 2 * per;
    float* cb = ws + 3 * per;

    const int M = B_SZ * L_SEQ;
    dim3 blk(256);
    dim3 gg(EMB / 128, M / 128);

    gemm_bias<1><<<gg, blk, 0, stream>>>(x,  Wq, bq, qb);
    gemm_bias<1><<<gg, blk, 0, stream>>>(x,  Wk, bk, kb);
    gemm_bias<1><<<gg, blk, 0, stream>>>(x,  Wv, bv, vb);
    attn_kernel<<<dim3(L_SEQ / 64, B_SZ * NH), blk, 0, stream>>>(qb, kb, vb, cb);
    gemm_bias<0><<<gg, blk, 0, stream>>>(cb, Wo, bo, out);
}

// Round 3
// 1013.175 us; speedup vs baseline: 2.1008x; 2.1008x over previous
//
#include <hip/hip_runtime.h>
#include <math.h>

#define B_SZ  2
#define L_SEQ 8192
#define EMB   1024
#define NH    16
#define HDIM  64
#define WIN   128
#define MROWS (B_SZ*L_SEQ)

typedef __attribute__((ext_vector_type(8))) short bf16x8;
typedef __attribute__((ext_vector_type(4))) float f32x4;

__device__ __forceinline__ unsigned short f2bf(float x) {
    unsigned u = __float_as_uint(x);
    u += 0x7fff + ((u >> 16) & 1);          // round-to-nearest-even
    return (unsigned short)(u >> 16);
}
__device__ __forceinline__ float bf2f(unsigned short h) {
    return __uint_as_float(((unsigned)h) << 16);
}
__device__ __forceinline__ void gload16(const void* g, void* l) {
    __builtin_amdgcn_global_load_lds(
        (const __attribute__((address_space(1))) unsigned int*)g,
        (__attribute__((address_space(3))) unsigned int*)l, 16, 0, 0);
}

// ---------------- fp32 -> bf16 hi/lo split ----------------
__global__ __launch_bounds__(256)
void split_kernel(const float* __restrict__ in, unsigned short* __restrict__ hi,
                  unsigned short* __restrict__ lo)
{
    int i = (blockIdx.x * 256 + threadIdx.x) * 4;
    float4 v = *(const float4*)(in + i);
    ushort4 h, l;
    h.x = f2bf(v.x); l.x = f2bf(v.x - bf2f(h.x));
    h.y = f2bf(v.y); l.y = f2bf(v.y - bf2f(h.y));
    h.z = f2bf(v.z); l.z = f2bf(v.z - bf2f(h.z));
    h.w = f2bf(v.w); l.w = f2bf(v.w - bf2f(h.w));
    *(ushort4*)(hi + i) = h;
    *(ushort4*)(lo + i) = l;
}

// ---------------- split-bf16 MFMA GEMM: C = A @ B^T + bias ----------------
// A: (M,1024) as hi/lo bf16 row-major; B: (1024,1024) as hi/lo bf16 row-major.
// m97 structure: 128x128 tile, BK=32, global_load_lds staging, 4 waves 2x2,
// each wave 4x4 of 16x16x32 MFMA tiles, 3 MFMA per tile (hi*hi+hi*lo+lo*hi).
template<int LAYOUT>
__global__ __launch_bounds__(256)
void gemm_mfma(const unsigned short* __restrict__ Ah, const unsigned short* __restrict__ Al,
               const unsigned short* __restrict__ Bh, const unsigned short* __restrict__ Bl,
               const float* __restrict__ bias, float* __restrict__ C)
{
    constexpr int K = EMB, N = EMB;
    __shared__ unsigned short smem[4 * 128 * 32];   // 32 KB, no padding (DMA dest)
    unsigned short* Ahs = smem;
    unsigned short* Als = smem + 128 * 32;
    unsigned short* Bhs = smem + 2 * 128 * 32;
    unsigned short* Bls = smem + 3 * 128 * 32;

    const int t = threadIdx.x;
    const int wave = t >> 6, lane = t & 63;
    const int bm = blockIdx.y * 128, bn = blockIdx.x * 128;

    // staging: thread t covers row (sweep*64 + t>>2), bf16 cols (t&3)*8..+8
    const int srow = t >> 2;
    const int scol = (t & 3) * 8;
    const size_t gA0 = (size_t)(bm + srow) * K + scol;
    const size_t gA1 = (size_t)(bm + 64 + srow) * K + scol;
    const size_t gB0 = (size_t)(bn + srow) * K + scol;
    const size_t gB1 = (size_t)(bn + 64 + srow) * K + scol;
    const int lb0 = (wave * 16) * 64;          // wave-uniform LDS byte base, sweep 0
    const int lb1 = (64 + wave * 16) * 64;     // sweep 1

    const int wr = wave >> 1, wc = wave & 1;
    const int frow = lane & 15, fk = (lane >> 4) * 16;   // fragment addr pieces (bytes)
    int aoff[4], boff[4];
    #pragma unroll
    for (int i = 0; i < 4; i++) {
        aoff[i] = (wr * 64 + i * 16 + frow) * 64 + fk;
        boff[i] = (wc * 64 + i * 16 + frow) * 64 + fk;
    }

    f32x4 acc[4][4] = {};

    for (int k0 = 0; k0 < K; k0 += 32) {
        gload16(Ah + gA0 + k0, (char*)Ahs + lb0);
        gload16(Ah + gA1 + k0, (char*)Ahs + lb1);
        gload16(Al + gA0 + k0, (char*)Als + lb0);
        gload16(Al + gA1 + k0, (char*)Als + lb1);
        gload16(Bh + gB0 + k0, (char*)Bhs + lb0);
        gload16(Bh + gB1 + k0, (char*)Bhs + lb1);
        gload16(Bl + gB0 + k0, (char*)Bls + lb0);
        gload16(Bl + gB1 + k0, (char*)Bls + lb1);
        __syncthreads();

        bf16x8 ah[4], al[4], bh[4], bl[4];
        #pragma unroll
        for (int i = 0; i < 4; i++) {
            ah[i] = *(const bf16x8*)((const char*)Ahs + aoff[i]);
            al[i] = *(const bf16x8*)((const char*)Als + aoff[i]);
            bh[i] = *(const bf16x8*)((const char*)Bhs + boff[i]);
            bl[i] = *(const bf16x8*)((const char*)Bls + boff[i]);
        }
        #pragma unroll
        for (int i = 0; i < 4; i++)
            #pragma unroll
            for (int j = 0; j < 4; j++) {
                acc[i][j] = __builtin_amdgcn_mfma_f32_16x16x32_bf16(ah[i], bh[j], acc[i][j], 0, 0, 0);
                acc[i][j] = __builtin_amdgcn_mfma_f32_16x16x32_bf16(ah[i], bl[j], acc[i][j], 0, 0, 0);
                acc[i][j] = __builtin_amdgcn_mfma_f32_16x16x32_bf16(al[i], bh[j], acc[i][j], 0, 0, 0);
            }
        __syncthreads();
    }

    // epilogue: C/D layout col=lane&15, row=(lane>>4)*4+reg
    const int crow = (lane >> 4) * 4;
    const int ccol = lane & 15;
    #pragma unroll
    for (int i = 0; i < 4; i++) {
        int m0 = bm + wr * 64 + i * 16 + crow;
        #pragma unroll
        for (int j = 0; j < 4; j++) {
            int n = bn + wc * 64 + j * 16 + ccol;
            float bvv = bias[n];
            #pragma unroll
            for (int r = 0; r < 4; r++) {
                float val = acc[i][j][r] + bvv;
                int mm = m0 + r;
                if (LAYOUT == 0) {
                    C[(size_t)mm * N + n] = val;
                } else {
                    int bb = mm >> 13, l = mm & (L_SEQ - 1);
                    int h = n >> 6, d = n & 63;
                    C[((size_t)(bb * NH + h) * L_SEQ + l) * HDIM + d] = val;
                }
            }
        }
    }
}

// ---------------- banded flash attention (fp32) ----------------
__global__ __launch_bounds__(256)
void attn_kernel(const float* __restrict__ qb, const float* __restrict__ kb,
                 const float* __restrict__ vb, float* __restrict__ ctx)
{
    __shared__ float Qs[HDIM * 68];
    __shared__ float KVs[64 * 68];
    __shared__ float Ps[64 * 68];
    __shared__ float red[4][64];
    __shared__ float m_run[64], l_run[64], alf[64];

    const int t  = threadIdx.x;
    const int tx = t & 15, ty = t >> 4;
    const int bh = blockIdx.y;
    const int q0 = blockIdx.x * 64;
    const float* qp = qb + ((size_t)bh * L_SEQ + q0) * HDIM;
    const float* kp = kb + (size_t)bh * L_SEQ * HDIM;
    const float* vp = vb + (size_t)bh * L_SEQ * HDIM;

    #pragma unroll
    for (int i = 0; i < 4; i++) {
        int fid = i * 256 + t;
        int r  = fid >> 4;
        int d0 = (fid & 15) << 2;
        float4 v = *(const float4*)(qp + (size_t)r * HDIM + d0);
        Qs[(d0+0)*68 + r] = v.x * 0.125f;
        Qs[(d0+1)*68 + r] = v.y * 0.125f;
        Qs[(d0+2)*68 + r] = v.z * 0.125f;
        Qs[(d0+3)*68 + r] = v.w * 0.125f;
    }
    if (t < 64) { m_run[t] = -3e38f; l_run[t] = 0.0f; }
    float o[4][4] = {};
    __syncthreads();

    for (int kt = 0; kt < 5; kt++) {
        const int p0 = q0 - WIN + kt * 64;
        #pragma unroll
        for (int i = 0; i < 4; i++) {
            int fid = i * 256 + t;
            int c  = fid >> 4;
            int d0 = (fid & 15) << 2;
            int p  = p0 + c;
            float4 v = make_float4(0.f, 0.f, 0.f, 0.f);
            if (p >= 0 && p < L_SEQ) v = *(const float4*)(kp + (size_t)p * HDIM + d0);
            KVs[(d0+0)*68 + c] = v.x;
            KVs[(d0+1)*68 + c] = v.y;
            KVs[(d0+2)*68 + c] = v.z;
            KVs[(d0+3)*68 + c] = v.w;
        }
        __syncthreads();
        float s[4][4] = {};
        #pragma unroll
        for (int d = 0; d < HDIM; d++) {
            float a[4], b[4];
            *(float4*)a = *(const float4*)&Qs[d*68 + ty*4];
            *(float4*)b = *(const float4*)&KVs[d*68 + tx*4];
            #pragma unroll
            for (int i = 0; i < 4; i++)
                #pragma unroll
                for (int j = 0; j < 4; j++)
                    s[i][j] = fmaf(a[i], b[j], s[i][j]);
        }
        #pragma unroll
        for (int i = 0; i < 4; i++)
            #pragma unroll
            for (int j = 0; j < 4; j++) {
                int r = ty*4 + i, c = tx*4 + j;
                int p = p0 + c;
                int delta = p - (q0 + r);
                if (p < 0 || p >= L_SEQ || delta < -WIN || delta > WIN)
                    s[i][j] = -3e38f;
            }
        __syncthreads();
        #pragma unroll
        for (int i = 0; i < 4; i++)
            #pragma unroll
            for (int j = 0; j < 4; j++)
                Ps[(tx*4+j)*68 + ty*4 + i] = s[i][j];
        #pragma unroll
        for (int i = 0; i < 4; i++) {
            int fid = i * 256 + t;
            int c  = fid >> 4;
            int d0 = (fid & 15) << 2;
            int p  = p0 + c;
            float4 v = make_float4(0.f, 0.f, 0.f, 0.f);
            if (p >= 0 && p < L_SEQ) v = *(const float4*)(vp + (size_t)p * HDIM + d0);
            *(float4*)&KVs[c*68 + d0] = v;
        }
        __syncthreads();
        {
            int r = t & 63, ch = t >> 6;
            float mx = -3e38f;
            #pragma unroll
            for (int cc = 0; cc < 16; cc++)
                mx = fmaxf(mx, Ps[(ch*16+cc)*68 + r]);
            red[ch][r] = mx;
        }
        __syncthreads();
        if (t < 64) {
            float mloc = fmaxf(fmaxf(red[0][t], red[1][t]),
                               fmaxf(red[2][t], red[3][t]));
            float mold = m_run[t];
            float mnew = fmaxf(mold, mloc);
            m_run[t] = mnew;
            alf[t] = __expf(mold - mnew);
        }
        __syncthreads();
        {
            int r = t & 63, ch = t >> 6;
            float mnew = m_run[r];
            float sum = 0.0f;
            #pragma unroll
            for (int cc = 0; cc < 16; cc++) {
                int c = ch*16 + cc;
                float pv = __expf(Ps[c*68 + r] - mnew);
                Ps[c*68 + r] = pv;
                sum += pv;
            }
            red[ch][r] = sum;
        }
        __syncthreads();
        if (t < 64)
            l_run[t] = l_run[t] * alf[t]
                     + red[0][t] + red[1][t] + red[2][t] + red[3][t];
        float al[4];
        #pragma unroll
        for (int i = 0; i < 4; i++) al[i] = alf[ty*4 + i];
        #pragma unroll
        for (int i = 0; i < 4; i++)
            #pragma unroll
            for (int j = 0; j < 4; j++) o[i][j] *= al[i];
        #pragma unroll
        for (int p = 0; p < 64; p++) {
            float a[4], b[4];
            *(float4*)a = *(const float4*)&Ps[p*68 + ty*4];
            *(float4*)b = *(const float4*)&KVs[p*68 + tx*4];
            #pragma unroll
            for (int i = 0; i < 4; i++)
                #pragma unroll
                for (int j = 0; j < 4; j++)
                    o[i][j] = fmaf(a[i], b[j], o[i][j]);
        }
        __syncthreads();
    }

    const int bb = bh >> 4, hh = bh & 15;
    #pragma unroll
    for (int i = 0; i < 4; i++) {
        float inv = 1.0f / l_run[ty*4 + i];
        int l = q0 + ty*4 + i;
        float4 r0 = make_float4(o[i][0]*inv, o[i][1]*inv,
                                o[i][2]*inv, o[i][3]*inv);
        *(float4*)(ctx + ((size_t)bb * L_SEQ + l) * EMB + hh * HDIM + tx*4) = r0;
    }
}

extern "C" void kernel_launch(void* const* d_in, const int* in_sizes, int n_in,
                              void* d_out, int out_size, void* d_ws, size_t ws_size,
                              hipStream_t stream) {
    const float* x  = (const float*)d_in[0];
    const float* Wq = (const float*)d_in[1];
    const float* Wk = (const float*)d_in[2];
    const float* Wv = (const float*)d_in[3];
    const float* Wo = (const float*)d_in[4];
    const float* bq = (const float*)d_in[5];
    const float* bk = (const float*)d_in[6];
    const float* bv = (const float*)d_in[7];
    const float* bo = (const float*)d_in[8];
    float* out = (float*)d_out;

    // Workspace budget: EXACTLY 4*per floats (= round-1 footprint, known good).
    float* ws = (float*)d_ws;
    const size_t per = (size_t)B_SZ * NH * L_SEQ * HDIM;   // 16.7M floats
    float* qb = ws;                 // q fp32 (B,H,L,64); later: ctx hi/lo splits
    float* kb = ws + per;
    float* vb = ws + 2 * per;       // v fp32; later: Wo hi/lo splits
    float* cb = ws + 3 * per;       // x hi/lo splits; later: ctx fp32

    unsigned short* xhi = (unsigned short*)cb;              // 2*per ushorts = cb exactly
    unsigned short* xlo = xhi + per;
    // Wq/Wk/Wv splits live in d_out (67 MB; fully overwritten by final GEMM).
    unsigned short* wsp = (unsigned short*)d_out;
    unsigned short* wqh = wsp;             unsigned short* wql = wsp + 1048576;
    unsigned short* wkh = wsp + 2*1048576; unsigned short* wkl = wsp + 3*1048576;
    unsigned short* wvh = wsp + 4*1048576; unsigned short* wvl = wsp + 5*1048576;
    // Wo splits reuse vb after attention; ctx splits reuse qb after attention.
    unsigned short* woh = (unsigned short*)vb; unsigned short* wol = woh + 1048576;
    unsigned short* chi = (unsigned short*)qb;
    unsigned short* clo = chi + per;

    dim3 blk(256);
    dim3 gg(EMB / 128, MROWS / 128);   // (8,128)

    split_kernel<<<(MROWS * EMB) / 1024, blk, 0, stream>>>(x, xhi, xlo);
    split_kernel<<<(EMB * EMB) / 1024, blk, 0, stream>>>(Wq, wqh, wql);
    split_kernel<<<(EMB * EMB) / 1024, blk, 0, stream>>>(Wk, wkh, wkl);
    split_kernel<<<(EMB * EMB) / 1024, blk, 0, stream>>>(Wv, wvh, wvl);

    gemm_mfma<1><<<gg, blk, 0, stream>>>(xhi, xlo, wqh, wql, bq, qb);
    gemm_mfma<1><<<gg, blk, 0, stream>>>(xhi, xlo, wkh, wkl, bk, kb);
    gemm_mfma<1><<<gg, blk, 0, stream>>>(xhi, xlo, wvh, wvl, bv, vb);

    attn_kernel<<<dim3(L_SEQ / 64, B_SZ * NH), blk, 0, stream>>>(qb, kb, vb, cb);

    split_kernel<<<(MROWS * EMB) / 1024, blk, 0, stream>>>(cb, chi, clo);
    split_kernel<<<(EMB * EMB) / 1024, blk, 0, stream>>>(Wo, woh, wol);
    gemm_mfma<0><<<gg, blk, 0, stream>>>(chi, clo, woh, wol, bo, out);
}

// Round 4
// 748.893 us; speedup vs baseline: 2.8422x; 1.3529x over previous
//
#include <hip/hip_runtime.h>
#include <math.h>

#define B_SZ  2
#define L_SEQ 8192
#define EMB   1024
#define NH    16
#define HDIM  64
#define WIN   128
#define MROWS (B_SZ*L_SEQ)

typedef __attribute__((ext_vector_type(8))) short bf16x8;
typedef __attribute__((ext_vector_type(4))) float f32x4;

__device__ __forceinline__ unsigned short f2bf(float x) {
    unsigned u = __float_as_uint(x);
    u += 0x7fff + ((u >> 16) & 1);          // round-to-nearest-even
    return (unsigned short)(u >> 16);
}
__device__ __forceinline__ float bf2f(unsigned short h) {
    return __uint_as_float(((unsigned)h) << 16);
}
__device__ __forceinline__ void gload16(const void* g, void* l) {
    __builtin_amdgcn_global_load_lds(
        (const __attribute__((address_space(1))) unsigned int*)g,
        (__attribute__((address_space(3))) unsigned int*)l, 16, 0, 0);
}

// ---------------- fp32 -> bf16 hi/lo split ----------------
__global__ __launch_bounds__(256)
void split_kernel(const float* __restrict__ in, unsigned short* __restrict__ hi,
                  unsigned short* __restrict__ lo)
{
    int i = (blockIdx.x * 256 + threadIdx.x) * 4;
    float4 v = *(const float4*)(in + i);
    ushort4 h, l;
    h.x = f2bf(v.x); l.x = f2bf(v.x - bf2f(h.x));
    h.y = f2bf(v.y); l.y = f2bf(v.y - bf2f(h.y));
    h.z = f2bf(v.z); l.z = f2bf(v.z - bf2f(h.z));
    h.w = f2bf(v.w); l.w = f2bf(v.w - bf2f(h.w));
    *(ushort4*)(hi + i) = h;
    *(ushort4*)(lo + i) = l;
}

// ---------------- split-bf16 MFMA GEMM: C = A @ B^T + bias ----------------
// LAYOUT 0: fp32 C[m][n].
// LAYOUT 1: split hi/lo scatter to (B,H,L,64), val *= scale (q: scale=1/8).
// LAYOUT 2: split hi/lo scatter TRANSPOSED to (B,H,64,L)  (for V^T).
template<int LAYOUT>
__global__ __launch_bounds__(256)
void gemm_mfma(const unsigned short* __restrict__ Ah, const unsigned short* __restrict__ Al,
               const unsigned short* __restrict__ Bh, const unsigned short* __restrict__ Bl,
               const float* __restrict__ bias, float* __restrict__ C,
               unsigned short* __restrict__ Chi, unsigned short* __restrict__ Clo,
               float scale)
{
    constexpr int K = EMB, N = EMB;
    __shared__ unsigned short smem[4 * 128 * 32];   // 32 KB, no padding (DMA dest)
    unsigned short* Ahs = smem;
    unsigned short* Als = smem + 128 * 32;
    unsigned short* Bhs = smem + 2 * 128 * 32;
    unsigned short* Bls = smem + 3 * 128 * 32;

    const int t = threadIdx.x;
    const int wave = t >> 6, lane = t & 63;
    const int bm = blockIdx.y * 128, bn = blockIdx.x * 128;

    const int srow = t >> 2;
    const int scol = (t & 3) * 8;
    const size_t gA0 = (size_t)(bm + srow) * K + scol;
    const size_t gA1 = (size_t)(bm + 64 + srow) * K + scol;
    const size_t gB0 = (size_t)(bn + srow) * K + scol;
    const size_t gB1 = (size_t)(bn + 64 + srow) * K + scol;
    const int lb0 = (wave * 16) * 64;
    const int lb1 = (64 + wave * 16) * 64;

    const int wr = wave >> 1, wc = wave & 1;
    const int frow = lane & 15, fk = (lane >> 4) * 16;
    int aoff[4], boff[4];
    #pragma unroll
    for (int i = 0; i < 4; i++) {
        aoff[i] = (wr * 64 + i * 16 + frow) * 64 + fk;
        boff[i] = (wc * 64 + i * 16 + frow) * 64 + fk;
    }

    f32x4 acc[4][4] = {};

    for (int k0 = 0; k0 < K; k0 += 32) {
        gload16(Ah + gA0 + k0, (char*)Ahs + lb0);
        gload16(Ah + gA1 + k0, (char*)Ahs + lb1);
        gload16(Al + gA0 + k0, (char*)Als + lb0);
        gload16(Al + gA1 + k0, (char*)Als + lb1);
        gload16(Bh + gB0 + k0, (char*)Bhs + lb0);
        gload16(Bh + gB1 + k0, (char*)Bhs + lb1);
        gload16(Bl + gB0 + k0, (char*)Bls + lb0);
        gload16(Bl + gB1 + k0, (char*)Bls + lb1);
        __syncthreads();

        bf16x8 ah[4], al[4], bh[4], bl[4];
        #pragma unroll
        for (int i = 0; i < 4; i++) {
            ah[i] = *(const bf16x8*)((const char*)Ahs + aoff[i]);
            al[i] = *(const bf16x8*)((const char*)Als + aoff[i]);
            bh[i] = *(const bf16x8*)((const char*)Bhs + boff[i]);
            bl[i] = *(const bf16x8*)((const char*)Bls + boff[i]);
        }
        #pragma unroll
        for (int i = 0; i < 4; i++)
            #pragma unroll
            for (int j = 0; j < 4; j++) {
                acc[i][j] = __builtin_amdgcn_mfma_f32_16x16x32_bf16(ah[i], bh[j], acc[i][j], 0, 0, 0);
                acc[i][j] = __builtin_amdgcn_mfma_f32_16x16x32_bf16(ah[i], bl[j], acc[i][j], 0, 0, 0);
                acc[i][j] = __builtin_amdgcn_mfma_f32_16x16x32_bf16(al[i], bh[j], acc[i][j], 0, 0, 0);
            }
        __syncthreads();
    }

    const int crow = (lane >> 4) * 4;
    const int ccol = lane & 15;
    #pragma unroll
    for (int i = 0; i < 4; i++) {
        int m0 = bm + wr * 64 + i * 16 + crow;
        #pragma unroll
        for (int j = 0; j < 4; j++) {
            int n = bn + wc * 64 + j * 16 + ccol;
            float bvv = bias[n];
            if (LAYOUT == 0) {
                #pragma unroll
                for (int r = 0; r < 4; r++)
                    C[(size_t)(m0 + r) * N + n] = acc[i][j][r] + bvv;
            } else if (LAYOUT == 1) {
                int h = n >> 6, d = n & 63;
                #pragma unroll
                for (int r = 0; r < 4; r++) {
                    int mm = m0 + r;
                    int bb = mm >> 13, l = mm & (L_SEQ - 1);
                    float val = (acc[i][j][r] + bvv) * scale;
                    unsigned short hi = f2bf(val);
                    unsigned short lo = f2bf(val - bf2f(hi));
                    size_t idx = ((size_t)(bb * NH + h) * L_SEQ + l) * HDIM + d;
                    Chi[idx] = hi; Clo[idx] = lo;
                }
            } else {
                int h = n >> 6, d = n & 63;
                int bb = m0 >> 13, l0 = m0 & (L_SEQ - 1);
                ushort4 h4, l4;
                float v0 = acc[i][j][0] + bvv, v1 = acc[i][j][1] + bvv;
                float v2 = acc[i][j][2] + bvv, v3 = acc[i][j][3] + bvv;
                h4.x = f2bf(v0); l4.x = f2bf(v0 - bf2f(h4.x));
                h4.y = f2bf(v1); l4.y = f2bf(v1 - bf2f(h4.y));
                h4.z = f2bf(v2); l4.z = f2bf(v2 - bf2f(h4.z));
                h4.w = f2bf(v3); l4.w = f2bf(v3 - bf2f(h4.w));
                size_t idx = ((size_t)(bb * NH + h) * HDIM + d) * L_SEQ + l0;
                *(ushort4*)(Chi + idx) = h4;
                *(ushort4*)(Clo + idx) = l4;
            }
        }
    }
}

// ---------------- banded flash attention, MFMA ----------------
// block: 64 queries of one (b,h); 4 waves, wave w owns query rows 16w..16w+15.
// K staged [key][dim] bf16, V staged transposed [dim][key]; both XOR-swizzled
// (16B quad q of row r sits at slot q^(r&7)) via DMA source permutation.
__global__ __launch_bounds__(256)
void attn_mfma(const unsigned short* __restrict__ qh, const unsigned short* __restrict__ ql,
               const unsigned short* __restrict__ kh, const unsigned short* __restrict__ kl,
               const unsigned short* __restrict__ vth, const unsigned short* __restrict__ vtl,
               unsigned short* __restrict__ chi, unsigned short* __restrict__ clo)
{
    __shared__ unsigned short Kh[4096], Kl[4096], Vh[4096], Vl[4096];  // 8 KB each
    __shared__ unsigned Ps[4][16 * 68];   // per-wave P, packed hi | lo<<16

    const int t = threadIdx.x;
    const int wave = t >> 6, lane = t & 63;
    const int col = lane & 15, quad = lane >> 4;
    const int bh = blockIdx.y;
    const int q0 = blockIdx.x * 64;

    // Q A-fragments in registers (scale 1/8 already folded in by GEMM epilogue)
    const size_t qidx = ((size_t)bh * L_SEQ + q0 + wave * 16 + col) * HDIM + quad * 8;
    bf16x8 qfh[2], qfl[2];
    qfh[0] = *(const bf16x8*)(qh + qidx); qfh[1] = *(const bf16x8*)(qh + qidx + 32);
    qfl[0] = *(const bf16x8*)(ql + qidx); qfl[1] = *(const bf16x8*)(ql + qidx + 32);

    f32x4 o[4] = {};
    float mrun[4], lrun[4];
    #pragma unroll
    for (int r = 0; r < 4; r++) { mrun[r] = -3e38f; lrun[r] = 0.0f; }

    const int srow = t >> 3, sc = t & 7;
    unsigned* Pw = Ps[wave];

    for (int kt = 0; kt < 5; kt++) {
        const int p0 = q0 - WIN + kt * 64;
        if (p0 >= 0 && p0 + 64 <= L_SEQ) {
            #pragma unroll
            for (int sw = 0; sw < 2; sw++) {
                int row = sw * 32 + srow;           // key for K, dim for Vt
                int gq = sc ^ (row & 7);
                size_t kgi = ((size_t)bh * L_SEQ + p0 + row) * HDIM + gq * 8;
                size_t vgi = ((size_t)bh * HDIM + row) * L_SEQ + p0 + gq * 8;
                int lb = sw * 4096 + wave * 1024;
                gload16(kh + kgi, (char*)Kh + lb);
                gload16(kl + kgi, (char*)Kl + lb);
                gload16(vth + vgi, (char*)Vh + lb);
                gload16(vtl + vgi, (char*)Vl + lb);
            }
        } else {
            #pragma unroll
            for (int sw = 0; sw < 2; sw++) {
                int row = sw * 32 + srow;
                int gq = sc ^ (row & 7);
                int p = p0 + row;
                float4 zh = make_float4(0.f,0.f,0.f,0.f), zl = zh;
                if (p >= 0 && p < L_SEQ) {
                    size_t kgi = ((size_t)bh * L_SEQ + p) * HDIM + gq * 8;
                    zh = *(const float4*)(kh + kgi);
                    zl = *(const float4*)(kl + kgi);
                }
                *(float4*)((char*)Kh + row * 128 + sc * 16) = zh;
                *(float4*)((char*)Kl + row * 128 + sc * 16) = zl;
                int pv0 = p0 + gq * 8;
                float4 wh = make_float4(0.f,0.f,0.f,0.f), wl = wh;
                if (pv0 >= 0 && pv0 + 8 <= L_SEQ) {
                    size_t vgi = ((size_t)bh * HDIM + row) * L_SEQ + pv0;
                    wh = *(const float4*)(vth + vgi);
                    wl = *(const float4*)(vtl + vgi);
                }
                *(float4*)((char*)Vh + row * 128 + sc * 16) = wh;
                *(float4*)((char*)Vl + row * 128 + sc * 16) = wl;
            }
        }
        __syncthreads();

        // ---- S = Q K^T (3-pass split) ----
        f32x4 s[4] = {};
        #pragma unroll
        for (int ks = 0; ks < 2; ks++)
            #pragma unroll
            for (int n = 0; n < 4; n++) {
                int key = n * 16 + col;
                int off = key * 128 + (((ks * 4 + quad) ^ (col & 7)) * 16);
                bf16x8 kfh = *(const bf16x8*)((const char*)Kh + off);
                bf16x8 kfl = *(const bf16x8*)((const char*)Kl + off);
                s[n] = __builtin_amdgcn_mfma_f32_16x16x32_bf16(qfh[ks], kfh, s[n], 0, 0, 0);
                s[n] = __builtin_amdgcn_mfma_f32_16x16x32_bf16(qfh[ks], kfl, s[n], 0, 0, 0);
                s[n] = __builtin_amdgcn_mfma_f32_16x16x32_bf16(qfl[ks], kfh, s[n], 0, 0, 0);
            }

        // ---- band + bounds mask (C layout: row=quad*4+r, col=key) ----
        const int rowb = q0 + wave * 16 + quad * 4;
        #pragma unroll
        for (int n = 0; n < 4; n++)
            #pragma unroll
            for (int r = 0; r < 4; r++) {
                int p = p0 + n * 16 + col;
                int dlt = p - (rowb + r);
                if (p < 0 || p >= L_SEQ || dlt < -WIN || dlt > WIN)
                    s[n][r] = -3e38f;
            }

        // ---- row max via shuffle over the 16 col-lanes ----
        float mx[4];
        #pragma unroll
        for (int r = 0; r < 4; r++)
            mx[r] = fmaxf(fmaxf(s[0][r], s[1][r]), fmaxf(s[2][r], s[3][r]));
        #pragma unroll
        for (int x = 1; x < 16; x <<= 1)
            #pragma unroll
            for (int r = 0; r < 4; r++)
                mx[r] = fmaxf(mx[r], __shfl_xor(mx[r], x, 64));
        float alpha[4];
        #pragma unroll
        for (int r = 0; r < 4; r++) {
            float mn = fmaxf(mrun[r], mx[r]);
            alpha[r] = __expf(mrun[r] - mn);
            mrun[r] = mn;
        }

        // ---- exp, row sum, pack P(hi,lo) to per-wave LDS ----
        float sm[4] = {0.f, 0.f, 0.f, 0.f};
        #pragma unroll
        for (int n = 0; n < 4; n++)
            #pragma unroll
            for (int r = 0; r < 4; r++) {
                float pv = __expf(s[n][r] - mrun[r]);
                sm[r] += pv;
                unsigned short ph = f2bf(pv);
                unsigned short pl = f2bf(pv - bf2f(ph));
                Pw[(quad * 4 + r) * 68 + n * 16 + col] = (unsigned)ph | ((unsigned)pl << 16);
            }
        #pragma unroll
        for (int x = 1; x < 16; x <<= 1)
            #pragma unroll
            for (int r = 0; r < 4; r++)
                sm[r] += __shfl_xor(sm[r], x, 64);
        #pragma unroll
        for (int r = 0; r < 4; r++)
            lrun[r] = lrun[r] * alpha[r] + sm[r];
        #pragma unroll
        for (int n = 0; n < 4; n++)
            #pragma unroll
            for (int r = 0; r < 4; r++)
                o[n][r] *= alpha[r];

        // ---- O += P @ V (3-pass; P A-frags from per-wave LDS) ----
        #pragma unroll
        for (int ks = 0; ks < 2; ks++) {
            unsigned pw[8];
            int pidx = col * 68 + ks * 32 + quad * 8;
            *(uint4*)&pw[0] = *(const uint4*)&Pw[pidx];
            *(uint4*)&pw[4] = *(const uint4*)&Pw[pidx + 4];
            union { unsigned short u[8]; bf16x8 v; } ph, pl;
            #pragma unroll
            for (int j = 0; j < 8; j++) {
                ph.u[j] = (unsigned short)pw[j];
                pl.u[j] = (unsigned short)(pw[j] >> 16);
            }
            #pragma unroll
            for (int n = 0; n < 4; n++) {
                int dd = n * 16 + col;
                int off = dd * 128 + (((ks * 4 + quad) ^ (col & 7)) * 16);
                bf16x8 vfh = *(const bf16x8*)((const char*)Vh + off);
                bf16x8 vfl = *(const bf16x8*)((const char*)Vl + off);
                o[n] = __builtin_amdgcn_mfma_f32_16x16x32_bf16(ph.v, vfh, o[n], 0, 0, 0);
                o[n] = __builtin_amdgcn_mfma_f32_16x16x32_bf16(ph.v, vfl, o[n], 0, 0, 0);
                o[n] = __builtin_amdgcn_mfma_f32_16x16x32_bf16(pl.v, vfh, o[n], 0, 0, 0);
            }
        }
        __syncthreads();
    }

    // ---- normalize, split to bf16 hi/lo ctx (B,L,E) ----
    const int b = bh >> 4, h = bh & 15;
    #pragma unroll
    for (int r = 0; r < 4; r++) {
        float inv = 1.0f / lrun[r];
        int q = q0 + wave * 16 + quad * 4 + r;
        size_t base = ((size_t)b * L_SEQ + q) * EMB + h * HDIM;
        #pragma unroll
        for (int n = 0; n < 4; n++) {
            float val = o[n][r] * inv;
            unsigned short hi = f2bf(val);
            unsigned short lo = f2bf(val - bf2f(hi));
            chi[base + n * 16 + col] = hi;
            clo[base + n * 16 + col] = lo;
        }
    }
}

extern "C" void kernel_launch(void* const* d_in, const int* in_sizes, int n_in,
                              void* d_out, int out_size, void* d_ws, size_t ws_size,
                              hipStream_t stream) {
    const float* x  = (const float*)d_in[0];
    const float* Wq = (const float*)d_in[1];
    const float* Wk = (const float*)d_in[2];
    const float* Wv = (const float*)d_in[3];
    const float* Wo = (const float*)d_in[4];
    const float* bq = (const float*)d_in[5];
    const float* bk = (const float*)d_in[6];
    const float* bv = (const float*)d_in[7];
    const float* bo = (const float*)d_in[8];
    float* out = (float*)d_out;

    // ws budget: 4*per floats (round-1 footprint). All buffers bf16 halves.
    const size_t per = (size_t)B_SZ * NH * L_SEQ * HDIM;   // 16.7M elements
    unsigned short* w0 = (unsigned short*)d_ws;
    unsigned short* qhb = w0;             // [0,per)
    unsigned short* qlb = w0 + per;
    unsigned short* khb = w0 + 2 * per;
    unsigned short* klb = w0 + 3 * per;
    unsigned short* vth = w0 + 4 * per;   // V transposed (B,H,64,L)
    unsigned short* vtl = w0 + 5 * per;
    unsigned short* xhi = w0 + 6 * per;   // x splits; later: ctx hi/lo
    unsigned short* xlo = w0 + 7 * per;
    unsigned short* chi = xhi;            // ctx splits reuse x region (x dead)
    unsigned short* clo = xlo;
    // Wq/Wk/Wv splits in d_out (overwritten by final GEMM); Wo in q region.
    unsigned short* wsp = (unsigned short*)d_out;
    unsigned short* wqh = wsp;             unsigned short* wql = wsp + 1048576;
    unsigned short* wkh = wsp + 2*1048576; unsigned short* wkl = wsp + 3*1048576;
    unsigned short* wvh = wsp + 4*1048576; unsigned short* wvl = wsp + 5*1048576;
    unsigned short* woh = qhb;             unsigned short* wol = qhb + 1048576;

    dim3 blk(256);
    dim3 gg(EMB / 128, MROWS / 128);   // (8,128)

    split_kernel<<<(MROWS * EMB) / 1024, blk, 0, stream>>>(x, xhi, xlo);
    split_kernel<<<(EMB * EMB) / 1024, blk, 0, stream>>>(Wq, wqh, wql);
    split_kernel<<<(EMB * EMB) / 1024, blk, 0, stream>>>(Wk, wkh, wkl);
    split_kernel<<<(EMB * EMB) / 1024, blk, 0, stream>>>(Wv, wvh, wvl);

    gemm_mfma<1><<<gg, blk, 0, stream>>>(xhi, xlo, wqh, wql, bq, nullptr, qhb, qlb, 0.125f);
    gemm_mfma<1><<<gg, blk, 0, stream>>>(xhi, xlo, wkh, wkl, bk, nullptr, khb, klb, 1.0f);
    gemm_mfma<2><<<gg, blk, 0, stream>>>(xhi, xlo, wvh, wvl, bv, nullptr, vth, vtl, 1.0f);

    attn_mfma<<<dim3(L_SEQ / 64, B_SZ * NH), blk, 0, stream>>>(qhb, qlb, khb, klb, vth, vtl, chi, clo);

    split_kernel<<<(EMB * EMB) / 1024, blk, 0, stream>>>(Wo, woh, wol);
    gemm_mfma<0><<<gg, blk, 0, stream>>>(chi, clo, woh, wol, bo, out, nullptr, nullptr, 1.0f);
}

// Round 5
// 405.066 us; speedup vs baseline: 5.2548x; 1.8488x over previous
//
#include <hip/hip_runtime.h>
#include <math.h>

#define B_SZ  2
#define L_SEQ 8192
#define EMB   1024
#define NH    16
#define HDIM  64
#define WIN   128
#define MROWS (B_SZ*L_SEQ)

typedef __attribute__((ext_vector_type(8))) _Float16 f16x8;
typedef __attribute__((ext_vector_type(4))) _Float16 f16x4;
typedef __attribute__((ext_vector_type(4))) float f32x4;

__device__ __forceinline__ void gload16(const void* g, void* l) {
    __builtin_amdgcn_global_load_lds(
        (const __attribute__((address_space(1))) unsigned int*)g,
        (__attribute__((address_space(3))) unsigned int*)l, 16, 0, 0);
}

// ---------------- fp32 -> fp16 round ----------------
__global__ __launch_bounds__(256)
void round_kernel(const float* __restrict__ in, _Float16* __restrict__ out)
{
    int i = (blockIdx.x * 256 + threadIdx.x) * 4;
    float4 v = *(const float4*)(in + i);
    f16x4 o;
    o[0] = (_Float16)v.x; o[1] = (_Float16)v.y;
    o[2] = (_Float16)v.z; o[3] = (_Float16)v.w;
    *(f16x4*)(out + i) = o;
}

// ---------------- fused QKV GEMM (fp16 1-pass MFMA) ----------------
// 3072 blocks. XCD swizzle: all 24 col-blocks of a row-tile -> same XCD,
// temporally adjacent (ids k,k+8,...). Epilogue stages tile in LDS and
// writes coalesced 16B chunks: q/k -> (B,H,L,64) (q pre-scaled 1/8),
// v -> transposed (B,H,64,L).
__global__ __launch_bounds__(256)
void gemm_qkv(const _Float16* __restrict__ X,
              const _Float16* __restrict__ Wq, const _Float16* __restrict__ Wk,
              const _Float16* __restrict__ Wv,
              const float* __restrict__ bq, const float* __restrict__ bk,
              const float* __restrict__ bv,
              _Float16* __restrict__ qf, _Float16* __restrict__ kf,
              _Float16* __restrict__ vtf)
{
    constexpr int K = EMB;
    __shared__ char smem[34816];                    // loop: 16KB; epi: 128*136*2
    _Float16* As = (_Float16*)smem;                 // [128][32]
    _Float16* Bs = (_Float16*)(smem + 8192);

    const int id = blockIdx.x;
    const int row = (id / 192) * 8 + (id & 7);      // same XCD for a row's cols
    const int colq = (id >> 3) % 24;
    const int wsel = colq >> 3;                     // 0=q 1=k 2=v
    const int bm = row * 128, bn = (colq & 7) * 128;
    const _Float16* Bw = wsel == 0 ? Wq : wsel == 1 ? Wk : Wv;
    const float* bias = wsel == 0 ? bq : wsel == 1 ? bk : bv;
    const float scale = wsel == 0 ? 0.125f : 1.0f;

    const int t = threadIdx.x;
    const int wave = t >> 6, lane = t & 63;
    const int srow = t >> 2, scol = (t & 3) * 8;
    const size_t gA0 = (size_t)(bm + srow) * K + scol;
    const size_t gA1 = (size_t)(bm + 64 + srow) * K + scol;
    const size_t gB0 = (size_t)(bn + srow) * K + scol;
    const size_t gB1 = (size_t)(bn + 64 + srow) * K + scol;
    const int lb0 = wave * 1024, lb1 = 4096 + wave * 1024;

    const int wr = wave >> 1, wc = wave & 1;
    const int frow = lane & 15, quad = lane >> 4;
    int aoff[4], boff[4];
    #pragma unroll
    for (int i = 0; i < 4; i++) {
        aoff[i] = (wr * 64 + i * 16 + frow) * 64 + quad * 16;
        boff[i] = (wc * 64 + i * 16 + frow) * 64 + quad * 16;
    }

    f32x4 acc[4][4] = {};
    for (int k0 = 0; k0 < K; k0 += 32) {
        gload16(X + gA0 + k0, (char*)As + lb0);
        gload16(X + gA1 + k0, (char*)As + lb1);
        gload16(Bw + gB0 + k0, (char*)Bs + lb0);
        gload16(Bw + gB1 + k0, (char*)Bs + lb1);
        __syncthreads();
        f16x8 af[4], bf[4];
        #pragma unroll
        for (int i = 0; i < 4; i++) {
            af[i] = *(const f16x8*)((const char*)As + aoff[i]);
            bf[i] = *(const f16x8*)((const char*)Bs + boff[i]);
        }
        #pragma unroll
        for (int i = 0; i < 4; i++)
            #pragma unroll
            for (int j = 0; j < 4; j++)
                acc[i][j] = __builtin_amdgcn_mfma_f32_16x16x32_f16(af[i], bf[j], acc[i][j], 0, 0, 0);
        __syncthreads();
    }

    // ---- epilogue: stage fp16 tile in LDS (stride 136), coalesced store ----
    _Float16* Ct = (_Float16*)smem;
    const int ccol = lane & 15;
    if (wsel < 2) {
        #pragma unroll
        for (int i = 0; i < 4; i++)
            #pragma unroll
            for (int j = 0; j < 4; j++) {
                int nl = wc * 64 + j * 16 + ccol;
                float bvv = bias[bn + nl];
                #pragma unroll
                for (int r = 0; r < 4; r++) {
                    int ml = wr * 64 + i * 16 + quad * 4 + r;
                    Ct[ml * 136 + nl] = (_Float16)((acc[i][j][r] + bvv) * scale);
                }
            }
        __syncthreads();
        _Float16* dst = wsel == 0 ? qf : kf;
        #pragma unroll
        for (int pass = 0; pass < 8; pass++) {
            int chunk = pass * 256 + t;
            int ml = chunk >> 4, seg = chunk & 15;
            uint4 v = *(const uint4*)&Ct[ml * 136 + seg * 8];
            int m = bm + ml, bb = m >> 13, l = m & (L_SEQ - 1);
            int n = bn + seg * 8, h = n >> 6, d = n & 63;
            *(uint4*)&dst[((size_t)(bb * NH + h) * L_SEQ + l) * HDIM + d] = v;
        }
    } else {
        #pragma unroll
        for (int i = 0; i < 4; i++)
            #pragma unroll
            for (int j = 0; j < 4; j++) {
                int nl = wc * 64 + j * 16 + ccol;
                float bvv = bias[bn + nl];
                #pragma unroll
                for (int r = 0; r < 4; r++) {
                    int ml = wr * 64 + i * 16 + quad * 4 + r;
                    Ct[nl * 136 + ml] = (_Float16)(acc[i][j][r] + bvv);
                }
            }
        __syncthreads();
        #pragma unroll
        for (int pass = 0; pass < 8; pass++) {
            int chunk = pass * 256 + t;
            int nl = chunk >> 4, seg = chunk & 15;
            uint4 v = *(const uint4*)&Ct[nl * 136 + seg * 8];
            int n = bn + nl, h = n >> 6, d = n & 63;
            int bb = bm >> 13, l = (bm & (L_SEQ - 1)) + seg * 8;
            *(uint4*)&vtf[((size_t)(bb * NH + h) * HDIM + d) * L_SEQ + l] = v;
        }
    }
}

// ---------------- output GEMM (fp16 1-pass): out = ctx @ Wo^T + bo ----------
__global__ __launch_bounds__(256)
void gemm_out(const _Float16* __restrict__ A, const _Float16* __restrict__ Bw,
              const float* __restrict__ bias, float* __restrict__ C)
{
    constexpr int K = EMB, N = EMB;
    __shared__ char smem[16384];
    _Float16* As = (_Float16*)smem;
    _Float16* Bs = (_Float16*)(smem + 8192);

    const int id = blockIdx.x;
    const int row = (id / 64) * 8 + (id & 7);
    const int bm = row * 128, bn = ((id >> 3) & 7) * 128;

    const int t = threadIdx.x;
    const int wave = t >> 6, lane = t & 63;
    const int srow = t >> 2, scol = (t & 3) * 8;
    const size_t gA0 = (size_t)(bm + srow) * K + scol;
    const size_t gA1 = (size_t)(bm + 64 + srow) * K + scol;
    const size_t gB0 = (size_t)(bn + srow) * K + scol;
    const size_t gB1 = (size_t)(bn + 64 + srow) * K + scol;
    const int lb0 = wave * 1024, lb1 = 4096 + wave * 1024;

    const int wr = wave >> 1, wc = wave & 1;
    const int frow = lane & 15, quad = lane >> 4;
    int aoff[4], boff[4];
    #pragma unroll
    for (int i = 0; i < 4; i++) {
        aoff[i] = (wr * 64 + i * 16 + frow) * 64 + quad * 16;
        boff[i] = (wc * 64 + i * 16 + frow) * 64 + quad * 16;
    }

    f32x4 acc[4][4] = {};
    for (int k0 = 0; k0 < K; k0 += 32) {
        gload16(A + gA0 + k0, (char*)As + lb0);
        gload16(A + gA1 + k0, (char*)As + lb1);
        gload16(Bw + gB0 + k0, (char*)Bs + lb0);
        gload16(Bw + gB1 + k0, (char*)Bs + lb1);
        __syncthreads();
        f16x8 af[4], bf[4];
        #pragma unroll
        for (int i = 0; i < 4; i++) {
            af[i] = *(const f16x8*)((const char*)As + aoff[i]);
            bf[i] = *(const f16x8*)((const char*)Bs + boff[i]);
        }
        #pragma unroll
        for (int i = 0; i < 4; i++)
            #pragma unroll
            for (int j = 0; j < 4; j++)
                acc[i][j] = __builtin_amdgcn_mfma_f32_16x16x32_f16(af[i], bf[j], acc[i][j], 0, 0, 0);
        __syncthreads();
    }

    const int ccol = lane & 15;
    #pragma unroll
    for (int i = 0; i < 4; i++) {
        int m0 = bm + wr * 64 + i * 16 + quad * 4;
        #pragma unroll
        for (int j = 0; j < 4; j++) {
            int n = bn + wc * 64 + j * 16 + ccol;
            float bvv = bias[n];
            #pragma unroll
            for (int r = 0; r < 4; r++)
                C[(size_t)(m0 + r) * N + n] = acc[i][j][r] + bvv;
        }
    }
}

// ---------------- banded flash attention, fp16 1-pass MFMA ----------------
__global__ __launch_bounds__(256)
void attn_mfma(const _Float16* __restrict__ qf, const _Float16* __restrict__ kf,
               const _Float16* __restrict__ vtf, _Float16* __restrict__ cf)
{
    __shared__ _Float16 Kf[4096], Vf[4096];     // 8 KB each, XOR-swizzled
    __shared__ _Float16 Ps[4][16 * 72];         // per-wave P

    const int t = threadIdx.x;
    const int wave = t >> 6, lane = t & 63;
    const int col = lane & 15, quad = lane >> 4;
    const int bh = blockIdx.y;
    const int q0 = blockIdx.x * 64;

    const size_t qidx = ((size_t)bh * L_SEQ + q0 + wave * 16 + col) * HDIM + quad * 8;
    f16x8 qfr[2];
    qfr[0] = *(const f16x8*)(qf + qidx);
    qfr[1] = *(const f16x8*)(qf + qidx + 32);

    f32x4 o[4] = {};
    float mrun[4], lrun[4];
    #pragma unroll
    for (int r = 0; r < 4; r++) { mrun[r] = -3e38f; lrun[r] = 0.0f; }

    const int srow = t >> 3, sc = t & 7;
    _Float16* Pw = Ps[wave];

    for (int kt = 0; kt < 5; kt++) {
        const int p0 = q0 - WIN + kt * 64;
        const bool inb = (p0 >= 0) && (p0 + 64 <= L_SEQ);   // tiles all-in or all-out
        if (inb) {
            #pragma unroll
            for (int sw = 0; sw < 2; sw++) {
                int row = sw * 32 + srow;
                int gq = sc ^ (row & 7);
                size_t kgi = ((size_t)bh * L_SEQ + p0 + row) * HDIM + gq * 8;
                size_t vgi = ((size_t)bh * HDIM + row) * L_SEQ + p0 + gq * 8;
                int lb = sw * 4096 + wave * 1024;
                gload16(kf + kgi, (char*)Kf + lb);
                gload16(vtf + vgi, (char*)Vf + lb);
            }
        } else {
            uint4 z = make_uint4(0, 0, 0, 0);
            #pragma unroll
            for (int sw = 0; sw < 2; sw++) {
                *(uint4*)((char*)Kf + sw * 4096 + t * 16) = z;
                *(uint4*)((char*)Vf + sw * 4096 + t * 16) = z;
            }
        }
        __syncthreads();

        // ---- S = Q K^T ----
        f32x4 s[4] = {};
        #pragma unroll
        for (int ks = 0; ks < 2; ks++)
            #pragma unroll
            for (int n = 0; n < 4; n++) {
                int key = n * 16 + col;
                int off = key * 128 + (((ks * 4 + quad) ^ (col & 7)) * 16);
                f16x8 kfr = *(const f16x8*)((const char*)Kf + off);
                s[n] = __builtin_amdgcn_mfma_f32_16x16x32_f16(qfr[ks], kfr, s[n], 0, 0, 0);
            }

        // ---- band + bounds mask ----
        const int rowb = q0 + wave * 16 + quad * 4;
        #pragma unroll
        for (int n = 0; n < 4; n++)
            #pragma unroll
            for (int r = 0; r < 4; r++) {
                int p = p0 + n * 16 + col;
                int dlt = p - (rowb + r);
                if (p < 0 || p >= L_SEQ || dlt < -WIN || dlt > WIN)
                    s[n][r] = -3e38f;
            }

        // ---- row max (shuffle over 16 col-lanes) ----
        float mx[4];
        #pragma unroll
        for (int r = 0; r < 4; r++)
            mx[r] = fmaxf(fmaxf(s[0][r], s[1][r]), fmaxf(s[2][r], s[3][r]));
        #pragma unroll
        for (int x = 1; x < 16; x <<= 1)
            #pragma unroll
            for (int r = 0; r < 4; r++)
                mx[r] = fmaxf(mx[r], __shfl_xor(mx[r], x, 64));
        float alpha[4];
        #pragma unroll
        for (int r = 0; r < 4; r++) {
            float mn = fmaxf(mrun[r], mx[r]);
            alpha[r] = __expf(mrun[r] - mn);
            mrun[r] = mn;
        }

        // ---- exp, row sum, P -> per-wave LDS (fp16) ----
        float sm[4] = {0.f, 0.f, 0.f, 0.f};
        #pragma unroll
        for (int n = 0; n < 4; n++)
            #pragma unroll
            for (int r = 0; r < 4; r++) {
                float pv = __expf(s[n][r] - mrun[r]);
                sm[r] += pv;
                Pw[(quad * 4 + r) * 72 + n * 16 + col] = (_Float16)pv;
            }
        #pragma unroll
        for (int x = 1; x < 16; x <<= 1)
            #pragma unroll
            for (int r = 0; r < 4; r++)
                sm[r] += __shfl_xor(sm[r], x, 64);
        #pragma unroll
        for (int r = 0; r < 4; r++)
            lrun[r] = lrun[r] * alpha[r] + sm[r];
        #pragma unroll
        for (int n = 0; n < 4; n++)
            #pragma unroll
            for (int r = 0; r < 4; r++)
                o[n][r] *= alpha[r];

        // ---- O += P @ V ----
        #pragma unroll
        for (int ks = 0; ks < 2; ks++) {
            f16x8 pfr = *(const f16x8*)&Pw[col * 72 + ks * 32 + quad * 8];
            #pragma unroll
            for (int n = 0; n < 4; n++) {
                int dd = n * 16 + col;
                int off = dd * 128 + (((ks * 4 + quad) ^ (col & 7)) * 16);
                f16x8 vfr = *(const f16x8*)((const char*)Vf + off);
                o[n] = __builtin_amdgcn_mfma_f32_16x16x32_f16(pfr, vfr, o[n], 0, 0, 0);
            }
        }
        __syncthreads();
    }

    // ---- normalize, store ctx fp16 (B,L,E) ----
    const int b = bh >> 4, h = bh & 15;
    #pragma unroll
    for (int r = 0; r < 4; r++) {
        float inv = 1.0f / lrun[r];
        int q = q0 + wave * 16 + quad * 4 + r;
        size_t base = ((size_t)b * L_SEQ + q) * EMB + h * HDIM;
        #pragma unroll
        for (int n = 0; n < 4; n++)
            cf[base + n * 16 + col] = (_Float16)(o[n][r] * inv);
    }
}

extern "C" void kernel_launch(void* const* d_in, const int* in_sizes, int n_in,
                              void* d_out, int out_size, void* d_ws, size_t ws_size,
                              hipStream_t stream) {
    const float* x  = (const float*)d_in[0];
    const float* Wq = (const float*)d_in[1];
    const float* Wk = (const float*)d_in[2];
    const float* Wv = (const float*)d_in[3];
    const float* Wo = (const float*)d_in[4];
    const float* bq = (const float*)d_in[5];
    const float* bk = (const float*)d_in[6];
    const float* bv = (const float*)d_in[7];
    const float* bo = (const float*)d_in[8];
    float* out = (float*)d_out;

    const size_t per = (size_t)B_SZ * NH * L_SEQ * HDIM;   // 16.7M elements
    _Float16* w16 = (_Float16*)d_ws;
    _Float16* xf   = w16;             // fp16 x
    _Float16* qf   = w16 + per;       // (B,H,L,64), pre-scaled 1/8
    _Float16* kf   = w16 + 2 * per;   // (B,H,L,64)
    _Float16* vtf  = w16 + 3 * per;   // (B,H,64,L)
    _Float16* cf   = w16 + 4 * per;   // ctx (B,L,E)
    _Float16* wq16 = w16 + 5 * per;
    _Float16* wk16 = wq16 + 1048576;
    _Float16* wv16 = wq16 + 2 * 1048576;
    _Float16* wo16 = wq16 + 3 * 1048576;

    dim3 blk(256);
    round_kernel<<<(MROWS * EMB) / 1024, blk, 0, stream>>>(x, xf);
    round_kernel<<<(EMB * EMB) / 1024, blk, 0, stream>>>(Wq, wq16);
    round_kernel<<<(EMB * EMB) / 1024, blk, 0, stream>>>(Wk, wk16);
    round_kernel<<<(EMB * EMB) / 1024, blk, 0, stream>>>(Wv, wv16);
    round_kernel<<<(EMB * EMB) / 1024, blk, 0, stream>>>(Wo, wo16);

    gemm_qkv<<<3072, blk, 0, stream>>>(xf, wq16, wk16, wv16, bq, bk, bv, qf, kf, vtf);

    attn_mfma<<<dim3(L_SEQ / 64, B_SZ * NH), blk, 0, stream>>>(qf, kf, vtf, cf);

    gemm_out<<<1024, blk, 0, stream>>>(cf, wo16, bo, out);
}

// Round 6
// 388.969 us; speedup vs baseline: 5.4722x; 1.0414x over previous
//
#include <hip/hip_runtime.h>
#include <math.h>

#define B_SZ  2
#define L_SEQ 8192
#define EMB   1024
#define NH    16
#define HDIM  64
#define WIN   128
#define MROWS (B_SZ*L_SEQ)

typedef __attribute__((ext_vector_type(8))) _Float16 f16x8;
typedef __attribute__((ext_vector_type(4))) _Float16 f16x4;
typedef __attribute__((ext_vector_type(4))) float f32x4;

__device__ __forceinline__ void gload16(const void* g, void* l) {
    __builtin_amdgcn_global_load_lds(
        (const __attribute__((address_space(1))) unsigned int*)g,
        (__attribute__((address_space(3))) unsigned int*)l, 16, 0, 0);
}

// ---------------- fused fp32 -> fp16 rounds (x + 4 weights) ----------------
__global__ __launch_bounds__(256)
void round_all(const float* __restrict__ x,
               const float* __restrict__ wq, const float* __restrict__ wk,
               const float* __restrict__ wv, const float* __restrict__ wo,
               _Float16* __restrict__ xf, _Float16* __restrict__ q16,
               _Float16* __restrict__ k16, _Float16* __restrict__ v16,
               _Float16* __restrict__ o16)
{
    const size_t NX = (size_t)MROWS * EMB, NW = (size_t)EMB * EMB;
    size_t gid = ((size_t)blockIdx.x * 256 + threadIdx.x) * 4;
    const float* src; _Float16* dst; size_t off;
    if (gid < NX)               { src = x;  dst = xf;  off = gid; }
    else if (gid < NX + NW)     { src = wq; dst = q16; off = gid - NX; }
    else if (gid < NX + 2*NW)   { src = wk; dst = k16; off = gid - NX - 2*NW + NW; }
    else if (gid < NX + 3*NW)   { src = wv; dst = v16; off = gid - NX - 2*NW; }
    else                        { src = wo; dst = o16; off = gid - NX - 3*NW; }
    float4 v = *(const float4*)(src + off);
    f16x4 o;
    o[0] = (_Float16)v.x; o[1] = (_Float16)v.y;
    o[2] = (_Float16)v.z; o[3] = (_Float16)v.w;
    *(f16x4*)(dst + off) = o;
}

// ---------------- fused QKV GEMM, fp16, BK=64, XOR-swizzled LDS ----------
__global__ __launch_bounds__(256)
void gemm_qkv(const _Float16* __restrict__ X,
              const _Float16* __restrict__ Wq, const _Float16* __restrict__ Wk,
              const _Float16* __restrict__ Wv,
              const float* __restrict__ bq, const float* __restrict__ bk,
              const float* __restrict__ bv,
              _Float16* __restrict__ qf, _Float16* __restrict__ kf,
              _Float16* __restrict__ vtf)
{
    constexpr int K = EMB;
    __shared__ char smem[34816];                // loop: As 16K + Bs 16K; epi: 34K
    _Float16* As = (_Float16*)smem;             // [128][64], row stride 128 B
    _Float16* Bs = (_Float16*)(smem + 16384);

    const int id = blockIdx.x;
    const int row = (id / 192) * 8 + (id & 7);  // all 24 col-blocks of a row -> 1 XCD
    const int colq = (id >> 3) % 24;
    const int wsel = colq >> 3;                 // 0=q 1=k 2=v
    const int bm = row * 128, bn = (colq & 7) * 128;
    const _Float16* Bw = wsel == 0 ? Wq : wsel == 1 ? Wk : Wv;
    const float* bias = wsel == 0 ? bq : wsel == 1 ? bk : bv;
    const float scale = wsel == 0 ? 0.125f : 1.0f;

    const int t = threadIdx.x;
    const int wave = t >> 6, lane = t & 63;
    const int srow = t >> 3;                    // 0..31
    const int gq8 = ((t & 7) ^ (srow & 7)) * 8; // swizzled global quad
    size_t gA[4], gB[4];
    #pragma unroll
    for (int s = 0; s < 4; s++) {
        int r = s * 32 + srow;
        gA[s] = (size_t)(bm + r) * K + gq8;
        gB[s] = (size_t)(bn + r) * K + gq8;
    }
    const int lbw = wave * 1024;

    const int wr = wave >> 1, wc = wave & 1;
    const int frow = lane & 15, quad = lane >> 4;
    int aoff[4][2], boff[4][2];
    #pragma unroll
    for (int i = 0; i < 4; i++)
        #pragma unroll
        for (int ks = 0; ks < 2; ks++) {
            int slot = ((ks * 4 + quad) ^ (frow & 7)) * 16;
            aoff[i][ks] = (wr * 64 + i * 16 + frow) * 128 + slot;
            boff[i][ks] = (wc * 64 + i * 16 + frow) * 128 + slot;
        }

    f32x4 acc[4][4] = {};
    for (int k0 = 0; k0 < K; k0 += 64) {
        #pragma unroll
        for (int s = 0; s < 4; s++) {
            gload16(X  + gA[s] + k0, (char*)As + s * 4096 + lbw);
            gload16(Bw + gB[s] + k0, (char*)Bs + s * 4096 + lbw);
        }
        __syncthreads();
        #pragma unroll
        for (int ks = 0; ks < 2; ks++) {
            f16x8 af[4], bf[4];
            #pragma unroll
            for (int i = 0; i < 4; i++) {
                af[i] = *(const f16x8*)((const char*)As + aoff[i][ks]);
                bf[i] = *(const f16x8*)((const char*)Bs + boff[i][ks]);
            }
            #pragma unroll
            for (int i = 0; i < 4; i++)
                #pragma unroll
                for (int j = 0; j < 4; j++)
                    acc[i][j] = __builtin_amdgcn_mfma_f32_16x16x32_f16(af[i], bf[j], acc[i][j], 0, 0, 0);
        }
        __syncthreads();
    }

    // ---- epilogue: LDS staging, coalesced 16B stores ----
    _Float16* Ct = (_Float16*)smem;
    const int ccol = lane & 15;
    if (wsel < 2) {
        #pragma unroll
        for (int i = 0; i < 4; i++)
            #pragma unroll
            for (int j = 0; j < 4; j++) {
                int nl = wc * 64 + j * 16 + ccol;
                float bvv = bias[bn + nl];
                #pragma unroll
                for (int r = 0; r < 4; r++) {
                    int ml = wr * 64 + i * 16 + quad * 4 + r;
                    Ct[ml * 136 + nl] = (_Float16)((acc[i][j][r] + bvv) * scale);
                }
            }
        __syncthreads();
        _Float16* dst = wsel == 0 ? qf : kf;
        #pragma unroll
        for (int pass = 0; pass < 8; pass++) {
            int chunk = pass * 256 + t;
            int ml = chunk >> 4, seg = chunk & 15;
            uint4 v = *(const uint4*)&Ct[ml * 136 + seg * 8];
            int m = bm + ml, bb = m >> 13, l = m & (L_SEQ - 1);
            int n = bn + seg * 8, h = n >> 6, d = n & 63;
            *(uint4*)&dst[((size_t)(bb * NH + h) * L_SEQ + l) * HDIM + d] = v;
        }
    } else {
        #pragma unroll
        for (int i = 0; i < 4; i++)
            #pragma unroll
            for (int j = 0; j < 4; j++) {
                int nl = wc * 64 + j * 16 + ccol;
                float bvv = bias[bn + nl];
                #pragma unroll
                for (int r = 0; r < 4; r++) {
                    int ml = wr * 64 + i * 16 + quad * 4 + r;
                    Ct[nl * 136 + ml] = (_Float16)(acc[i][j][r] + bvv);
                }
            }
        __syncthreads();
        #pragma unroll
        for (int pass = 0; pass < 8; pass++) {
            int chunk = pass * 256 + t;
            int nl = chunk >> 4, seg = chunk & 15;
            uint4 v = *(const uint4*)&Ct[nl * 136 + seg * 8];
            int n = bn + nl, h = n >> 6, d = n & 63;
            int bb = bm >> 13, l = (bm & (L_SEQ - 1)) + seg * 8;
            *(uint4*)&vtf[((size_t)(bb * NH + h) * HDIM + d) * L_SEQ + l] = v;
        }
    }
}

// ---------------- output GEMM, fp16, BK=64 ----------------
__global__ __launch_bounds__(256)
void gemm_out(const _Float16* __restrict__ A, const _Float16* __restrict__ Bw,
              const float* __restrict__ bias, float* __restrict__ C)
{
    constexpr int K = EMB, N = EMB;
    __shared__ char smem[32768];
    _Float16* As = (_Float16*)smem;
    _Float16* Bs = (_Float16*)(smem + 16384);

    const int id = blockIdx.x;
    const int row = (id / 64) * 8 + (id & 7);
    const int bm = row * 128, bn = ((id >> 3) & 7) * 128;

    const int t = threadIdx.x;
    const int wave = t >> 6, lane = t & 63;
    const int srow = t >> 3;
    const int gq8 = ((t & 7) ^ (srow & 7)) * 8;
    size_t gA[4], gB[4];
    #pragma unroll
    for (int s = 0; s < 4; s++) {
        int r = s * 32 + srow;
        gA[s] = (size_t)(bm + r) * K + gq8;
        gB[s] = (size_t)(bn + r) * K + gq8;
    }
    const int lbw = wave * 1024;

    const int wr = wave >> 1, wc = wave & 1;
    const int frow = lane & 15, quad = lane >> 4;
    int aoff[4][2], boff[4][2];
    #pragma unroll
    for (int i = 0; i < 4; i++)
        #pragma unroll
        for (int ks = 0; ks < 2; ks++) {
            int slot = ((ks * 4 + quad) ^ (frow & 7)) * 16;
            aoff[i][ks] = (wr * 64 + i * 16 + frow) * 128 + slot;
            boff[i][ks] = (wc * 64 + i * 16 + frow) * 128 + slot;
        }

    f32x4 acc[4][4] = {};
    for (int k0 = 0; k0 < K; k0 += 64) {
        #pragma unroll
        for (int s = 0; s < 4; s++) {
            gload16(A  + gA[s] + k0, (char*)As + s * 4096 + lbw);
            gload16(Bw + gB[s] + k0, (char*)Bs + s * 4096 + lbw);
        }
        __syncthreads();
        #pragma unroll
        for (int ks = 0; ks < 2; ks++) {
            f16x8 af[4], bf[4];
            #pragma unroll
            for (int i = 0; i < 4; i++) {
                af[i] = *(const f16x8*)((const char*)As + aoff[i][ks]);
                bf[i] = *(const f16x8*)((const char*)Bs + boff[i][ks]);
            }
            #pragma unroll
            for (int i = 0; i < 4; i++)
                #pragma unroll
                for (int j = 0; j < 4; j++)
                    acc[i][j] = __builtin_amdgcn_mfma_f32_16x16x32_f16(af[i], bf[j], acc[i][j], 0, 0, 0);
        }
        __syncthreads();
    }

    const int ccol = lane & 15;
    #pragma unroll
    for (int i = 0; i < 4; i++) {
        int m0 = bm + wr * 64 + i * 16 + quad * 4;
        #pragma unroll
        for (int j = 0; j < 4; j++) {
            int n = bn + wc * 64 + j * 16 + ccol;
            float bvv = bias[n];
            #pragma unroll
            for (int r = 0; r < 4; r++)
                C[(size_t)(m0 + r) * N + n] = acc[i][j][r] + bvv;
        }
    }
}

// ---------------- banded flash attention, fp16 MFMA, 128-query tiles -------
__global__ __launch_bounds__(256)
void attn_mfma(const _Float16* __restrict__ qf, const _Float16* __restrict__ kf,
               const _Float16* __restrict__ vtf, _Float16* __restrict__ cf)
{
    __shared__ _Float16 Kf[4096], Vf[4096];     // 8 KB each, XOR-swizzled
    __shared__ _Float16 Ps[4][16 * 72];         // per-wave P (reused for g=0,1)

    const int t = threadIdx.x;
    const int wave = t >> 6, lane = t & 63;
    const int col = lane & 15, quad = lane >> 4;
    const int bh = blockIdx.y;
    const int q0 = blockIdx.x * 128;

    f16x8 qfr[2][2];
    #pragma unroll
    for (int g = 0; g < 2; g++) {
        size_t qidx = ((size_t)bh * L_SEQ + q0 + g * 64 + wave * 16 + col) * HDIM + quad * 8;
        qfr[g][0] = *(const f16x8*)(qf + qidx);
        qfr[g][1] = *(const f16x8*)(qf + qidx + 32);
    }

    f32x4 o[2][4] = {};
    float mrun[2][4], lrun[2][4];
    #pragma unroll
    for (int g = 0; g < 2; g++)
        #pragma unroll
        for (int r = 0; r < 4; r++) { mrun[g][r] = -3e38f; lrun[g][r] = 0.0f; }

    const int srow = t >> 3, sc = t & 7;
    _Float16* Pw = Ps[wave];

    for (int kt = 0; kt < 6; kt++) {
        const int p0 = q0 - WIN + kt * 64;
        if (p0 < 0 || p0 >= L_SEQ) continue;    // fully-OOB tile (block-uniform)
        #pragma unroll
        for (int sw = 0; sw < 2; sw++) {
            int row = sw * 32 + srow;
            int gq = sc ^ (row & 7);
            size_t kgi = ((size_t)bh * L_SEQ + p0 + row) * HDIM + gq * 8;
            size_t vgi = ((size_t)bh * HDIM + row) * L_SEQ + p0 + gq * 8;
            int lb = sw * 4096 + wave * 1024;
            gload16(kf + kgi, (char*)Kf + lb);
            gload16(vtf + vgi, (char*)Vf + lb);
        }
        __syncthreads();

        #pragma unroll
        for (int g = 0; g < 2; g++) {
            // ---- S = Q K^T ----
            f32x4 s[4] = {};
            #pragma unroll
            for (int ks = 0; ks < 2; ks++)
                #pragma unroll
                for (int n = 0; n < 4; n++) {
                    int off = (n * 16 + col) * 128 + (((ks * 4 + quad) ^ (col & 7)) * 16);
                    f16x8 kfr = *(const f16x8*)((const char*)Kf + off);
                    s[n] = __builtin_amdgcn_mfma_f32_16x16x32_f16(qfr[g][ks], kfr, s[n], 0, 0, 0);
                }
            // ---- band mask ----
            const int rowb = q0 + g * 64 + wave * 16 + quad * 4;
            #pragma unroll
            for (int n = 0; n < 4; n++)
                #pragma unroll
                for (int r = 0; r < 4; r++) {
                    int dlt = (p0 + n * 16 + col) - (rowb + r);
                    if (dlt < -WIN || dlt > WIN) s[n][r] = -3e38f;
                }
            // ---- row max (shuffle over 16 col-lanes) ----
            float mx[4];
            #pragma unroll
            for (int r = 0; r < 4; r++)
                mx[r] = fmaxf(fmaxf(s[0][r], s[1][r]), fmaxf(s[2][r], s[3][r]));
            #pragma unroll
            for (int x = 1; x < 16; x <<= 1)
                #pragma unroll
                for (int r = 0; r < 4; r++)
                    mx[r] = fmaxf(mx[r], __shfl_xor(mx[r], x, 64));
            float alpha[4];
            #pragma unroll
            for (int r = 0; r < 4; r++) {
                float mn = fmaxf(mrun[g][r], mx[r]);
                alpha[r] = __expf(mrun[g][r] - mn);
                mrun[g][r] = mn;
            }
            // ---- exp, row sum, P -> per-wave LDS ----
            float sm[4] = {0.f, 0.f, 0.f, 0.f};
            #pragma unroll
            for (int n = 0; n < 4; n++)
                #pragma unroll
                for (int r = 0; r < 4; r++) {
                    float pv = __expf(s[n][r] - mrun[g][r]);
                    sm[r] += pv;
                    Pw[(quad * 4 + r) * 72 + n * 16 + col] = (_Float16)pv;
                }
            #pragma unroll
            for (int x = 1; x < 16; x <<= 1)
                #pragma unroll
                for (int r = 0; r < 4; r++)
                    sm[r] += __shfl_xor(sm[r], x, 64);
            #pragma unroll
            for (int r = 0; r < 4; r++)
                lrun[g][r] = lrun[g][r] * alpha[r] + sm[r];
            #pragma unroll
            for (int n = 0; n < 4; n++)
                #pragma unroll
                for (int r = 0; r < 4; r++)
                    o[g][n][r] *= alpha[r];
            // ---- O += P @ V ----
            #pragma unroll
            for (int ks = 0; ks < 2; ks++) {
                f16x8 pfr = *(const f16x8*)&Pw[col * 72 + ks * 32 + quad * 8];
                #pragma unroll
                for (int n = 0; n < 4; n++) {
                    int off = (n * 16 + col) * 128 + (((ks * 4 + quad) ^ (col & 7)) * 16);
                    f16x8 vfr = *(const f16x8*)((const char*)Vf + off);
                    o[g][n] = __builtin_amdgcn_mfma_f32_16x16x32_f16(pfr, vfr, o[g][n], 0, 0, 0);
                }
            }
        }
        __syncthreads();
    }

    // ---- normalize, store ctx fp16 (B,L,E) ----
    const int b = bh >> 4, h = bh & 15;
    #pragma unroll
    for (int g = 0; g < 2; g++)
        #pragma unroll
        for (int r = 0; r < 4; r++) {
            float inv = 1.0f / lrun[g][r];
            int q = q0 + g * 64 + wave * 16 + quad * 4 + r;
            size_t base = ((size_t)b * L_SEQ + q) * EMB + h * HDIM;
            #pragma unroll
            for (int n = 0; n < 4; n++)
                cf[base + n * 16 + col] = (_Float16)(o[g][n][r] * inv);
        }
}

extern "C" void kernel_launch(void* const* d_in, const int* in_sizes, int n_in,
                              void* d_out, int out_size, void* d_ws, size_t ws_size,
                              hipStream_t stream) {
    const float* x  = (const float*)d_in[0];
    const float* Wq = (const float*)d_in[1];
    const float* Wk = (const float*)d_in[2];
    const float* Wv = (const float*)d_in[3];
    const float* Wo = (const float*)d_in[4];
    const float* bq = (const float*)d_in[5];
    const float* bk = (const float*)d_in[6];
    const float* bv = (const float*)d_in[7];
    const float* bo = (const float*)d_in[8];
    float* out = (float*)d_out;

    const size_t per = (size_t)B_SZ * NH * L_SEQ * HDIM;   // 16.7M elements
    _Float16* w16 = (_Float16*)d_ws;
    _Float16* xf   = w16;
    _Float16* qf   = w16 + per;       // (B,H,L,64), pre-scaled 1/8
    _Float16* kf   = w16 + 2 * per;
    _Float16* vtf  = w16 + 3 * per;   // (B,H,64,L)
    _Float16* cf   = w16 + 4 * per;   // ctx (B,L,E)
    _Float16* wq16 = w16 + 5 * per;
    _Float16* wk16 = wq16 + 1048576;
    _Float16* wv16 = wq16 + 2 * 1048576;
    _Float16* wo16 = wq16 + 3 * 1048576;

    dim3 blk(256);
    const int nround = (MROWS * EMB + 4 * EMB * EMB) / 1024;   // 20480
    round_all<<<nround, blk, 0, stream>>>(x, Wq, Wk, Wv, Wo, xf, wq16, wk16, wv16, wo16);

    gemm_qkv<<<3072, blk, 0, stream>>>(xf, wq16, wk16, wv16, bq, bk, bv, qf, kf, vtf);

    attn_mfma<<<dim3(L_SEQ / 128, B_SZ * NH), blk, 0, stream>>>(qf, kf, vtf, cf);

    gemm_out<<<1024, blk, 0, stream>>>(cf, wo16, bo, out);
}